// Round 1
// 400.036 us; speedup vs baseline: 1.0756x; 1.0756x over previous
//
#include <hip/hip_runtime.h>
#include <hip/hip_bf16.h>
#include <math.h>

#define NSTREAM 4
#define DIM     1024
#define BUSW    4096
#define NTOK    8192      // B*L = 4*2048
#define NPAD    288       // 256 (res) + 4 (pre) + 4 (post) + pad to 16*18
#define KSPLIT  4
#define KCH     1024      // BUSW / KSPLIT
#define BM      64
#define BK      32
#define OUT0    ((size_t)16 * 2048 * 1024)   // offset of branch_input in d_out

typedef short bf16x8 __attribute__((ext_vector_type(8)));
typedef float f32x4  __attribute__((ext_vector_type(4)));

__device__ __forceinline__ unsigned short f2bf(float f) {
    union { float f; unsigned int u; } x; x.f = f;
    unsigned int r = x.u + 0x7fffu + ((x.u >> 16) & 1u);
    return (unsigned short)(r >> 16);
}
__device__ __forceinline__ unsigned int pack2(float a, float b) {
    return (unsigned int)f2bf(a) | ((unsigned int)f2bf(b) << 16);
}

// ---------------------------------------------------------------------------
// Kernel 1: pack W''[n][k] = (gamma[k]+1) * [phi_res|phi_pre|phi_post|0][k][n]
// stored N-major, K-fast (bf16) so B-fragments are contiguous 16B reads.
// ---------------------------------------------------------------------------
__global__ void prep_w_kernel(const float* __restrict__ gamma,
                              const float* __restrict__ phi_res,
                              const float* __restrict__ phi_pre,
                              const float* __restrict__ phi_post,
                              unsigned short* __restrict__ W) {
    int idx = blockIdx.x * 256 + threadIdx.x;    // idx = n*4096 + k
    int n = idx >> 12;
    int k = idx & 4095;
    float v = 0.0f;
    if (n < 256)      v = phi_res[k * 256 + n];
    else if (n < 260) v = phi_pre[k * 4 + (n - 256)];
    else if (n < 264) v = phi_post[k * 4 + (n - 260)];
    v *= (gamma[k] + 1.0f);
    W[idx] = f2bf(v);
}

// ---------------------------------------------------------------------------
// Kernel 2: raw_part[kc][token][n] = sum_{k in kc-chunk} bus[token][k]*W''[n][k]
// MFMA 16x16x32 bf16. Block: 256 thr (4 waves), BM=64 tokens x NPAD=288 cols,
// BK=32, split-K over blockIdx.y. Wave w: rows (w>>1)*32, cols (w&1)*144.
// ---------------------------------------------------------------------------
__launch_bounds__(256, 2)
__global__ void gemm_raw_kernel(const float* __restrict__ residuals,
                                const unsigned short* __restrict__ W,
                                float* __restrict__ raw_part) {
    __shared__ unsigned short Alds[BM * BK];      // [row][k], k-fast
    __shared__ unsigned short Blds[NPAD * BK];    // [n][k],   k-fast

    const int tid = threadIdx.x;
    const int wid = tid >> 6, lane = tid & 63;
    const int tb = blockIdx.x, kc = blockIdx.y;
    const int row0 = tb * BM;

    f32x4 acc[2][9];
#pragma unroll
    for (int i = 0; i < 2; i++)
#pragma unroll
        for (int j = 0; j < 9; j++) acc[i][j] = (f32x4){0.f, 0.f, 0.f, 0.f};

    // A staging: thread -> (row = tid/4, 8 consecutive k at (tid%4)*8)
    const int arow = tid >> 2;
    const int akq  = (tid & 3) * 8;
    const int tok  = row0 + arow;
    const int bidx = tok >> 11, lidx = tok & 2047;
    // bus k = kc*1024 + (kt*32 + akq); stream = kc (since chunk < 1024)
    const float* abase = residuals +
        (((size_t)(bidx * 4 + kc) * 2048 + lidx) * 1024 + akq);
    const unsigned short* wbase = W + (size_t)kc * KCH;

    const int fr = lane & 15, hf = lane >> 4;
    const int wr = (wid >> 1) * 32;
    const int wc = (wid & 1) * 144;

    for (int kt = 0; kt < KCH / BK; kt++) {
        // stage A (fp32 -> bf16)
        const float* ap = abase + kt * BK;
        float4 f0 = *(const float4*)(ap);
        float4 f1 = *(const float4*)(ap + 4);
        uint4 ua;
        ua.x = pack2(f0.x, f0.y); ua.y = pack2(f0.z, f0.w);
        ua.z = pack2(f1.x, f1.y); ua.w = pack2(f1.z, f1.w);
        *(uint4*)&Alds[arow * BK + akq] = ua;
        // stage B: 288 rows x 32 k = 1152 16B chunks
#pragma unroll
        for (int i = 0; i < 5; i++) {
            int idx = i * 256 + tid;
            if (idx < (NPAD * BK) / 8) {
                int rn = idx >> 2, ko = (idx & 3) * 8;
                uint4 w = *(const uint4*)(wbase + (size_t)rn * BUSW + kt * BK + ko);
                *(uint4*)&Blds[rn * BK + ko] = w;
            }
        }
        __syncthreads();

        bf16x8 afrag[2], bfrag[9];
#pragma unroll
        for (int mt = 0; mt < 2; mt++)
            afrag[mt] = *(const bf16x8*)&Alds[(wr + mt * 16 + fr) * BK + hf * 8];
#pragma unroll
        for (int nt = 0; nt < 9; nt++)
            bfrag[nt] = *(const bf16x8*)&Blds[(wc + nt * 16 + fr) * BK + hf * 8];
#pragma unroll
        for (int mt = 0; mt < 2; mt++)
#pragma unroll
            for (int nt = 0; nt < 9; nt++)
                acc[mt][nt] = __builtin_amdgcn_mfma_f32_16x16x32_bf16(
                    afrag[mt], bfrag[nt], acc[mt][nt], 0, 0, 0);
        __syncthreads();
    }

    // epilogue: C/D mapping col=lane&15, row=(lane>>4)*4+reg
#pragma unroll
    for (int mt = 0; mt < 2; mt++)
#pragma unroll
        for (int nt = 0; nt < 9; nt++)
#pragma unroll
            for (int r = 0; r < 4; r++) {
                int token = row0 + wr + mt * 16 + hf * 4 + r;
                int col   = wc + nt * 16 + fr;
                raw_part[((size_t)kc * NTOK + token) * NPAD + col] = acc[mt][nt][r];
            }
}

// ---------------------------------------------------------------------------
// Kernel 3: per-token fused tail. 1 block (256 thr) per token.
// Sinkhorn runs in MULTIPLICATIVE domain (K = exp(Z) computed once; iterations
// are pure FMA+div), confined to wave 0 (wave-internal LDS ordering, no block
// barriers inside the loop). H_pre/H_post softmax runs on wave 1 in parallel.
// Block barrier count: 3 (was ~24).
// ---------------------------------------------------------------------------
__global__ void fused_tail_kernel(const float* __restrict__ residuals,
                                  const float* __restrict__ branch_output,
                                  const float* __restrict__ H_res_logits,
                                  const float* __restrict__ alpha_res_p,
                                  const float* __restrict__ H_pre_logits,
                                  const float* __restrict__ alpha_pre_p,
                                  const float* __restrict__ H_post_logits,
                                  const float* __restrict__ alpha_post_p,
                                  const float* __restrict__ raw_part,
                                  float* __restrict__ out) {
    const int t = blockIdx.x;
    const int b = t >> 11, l = t & 2047;
    const int tid = threadIdx.x;
    const int wid = tid >> 6, lane = tid & 63;

    __shared__ float busf[4096];
    __shared__ float Zl[256];      // K = exp(Z), then overwritten with S
    __shared__ float au[16], bv[16];
    __shared__ float extra[8];
    __shared__ float hpre[4], hpost[4];
    __shared__ float redbuf[4];

    // raw row sums over split-K partials (independent of bus load)
    float rsum = 0.f;
#pragma unroll
    for (int kc = 0; kc < 4; kc++)
        rsum += raw_part[((size_t)kc * NTOK + t) * NPAD + tid];
    float esum = 0.f;
    if (tid < 8) {
#pragma unroll
        for (int kc = 0; kc < 4; kc++)
            esum += raw_part[((size_t)kc * NTOK + t) * NPAD + 256 + tid];
    }

    // load bus (4 streams x 1024) + sum of squares
    const float* rbase = residuals + ((size_t)b * 4 * 2048 + l) * 1024;
    float sumsq = 0.f;
#pragma unroll
    for (int s = 0; s < 4; s++) {
        float4 v = *(const float4*)(rbase + (size_t)s * 2048 * 1024 + tid * 4);
        *(float4*)&busf[s * 1024 + tid * 4] = v;
        sumsq += v.x * v.x + v.y * v.y + v.z * v.z + v.w * v.w;
    }
#pragma unroll
    for (int off = 32; off > 0; off >>= 1) sumsq += __shfl_down(sumsq, off, 64);
    if (lane == 0) redbuf[wid] = sumsq;
    __syncthreads();                                   // barrier 1

    const float ss = redbuf[0] + redbuf[1] + redbuf[2] + redbuf[3];
    const float scale = 64.0f / fmaxf(sqrtf(ss), 1e-12f);  // sqrt(4096)/||bus||

    // K = exp(Z); Z = (alpha*scale*raw + logits)/tau. Z in [-161, ~2]: no max
    // subtraction needed; off-diagonal underflow to 0 matches reference ~1e-70.
    const float a_res = alpha_res_p[0];
    Zl[tid] = __expf((a_res * scale * rsum + H_res_logits[tid]) * 20.0f);
    if (tid < 8) extra[tid] = esum;

    // prefetch branch_output while Sinkhorn runs
    const float* bo = branch_output + ((size_t)b * 2048 + l) * 1024;
    float bor[4];
#pragma unroll
    for (int j = 0; j < 4; j++) bor[j] = bo[j * 256 + tid];

    __syncthreads();                                   // barrier 2

    if (wid == 0) {
        // Multiplicative Sinkhorn on lanes 0..15 of wave 0.
        // a[r] = (1/16)/(K b)[r];  b[c] = (1/16)/(K^T a)[c];  10 iterations.
        // Wave-internal LDS RAW is in-order per wave; sched_barrier(0) stops
        // the compiler from reordering across phases.
        const float c0 = 1.0f / 16.0f;
        const bool act = lane < 16;
        const int r = lane & 15;
        if (act) bv[r] = 1.0f;
        __builtin_amdgcn_sched_barrier(0);
        float a_own = 0.f;
        for (int it = 0; it < 10; it++) {
            if (act) {
                float s2 = 0.f;
#pragma unroll
                for (int c = 0; c < 16; c++) s2 += Zl[r * 16 + c] * bv[c];
                a_own = c0 / s2;
                au[r] = a_own;
            }
            __builtin_amdgcn_sched_barrier(0);
            if (act) {
                float s2 = 0.f;
#pragma unroll
                for (int rr = 0; rr < 16; rr++) s2 += Zl[rr * 16 + r] * au[rr];
                bv[r] = c0 / s2;
            }
            __builtin_amdgcn_sched_barrier(0);
        }
        // S = 16 * K * a_r * b_c, in place
        if (act) {
#pragma unroll
            for (int c = 0; c < 16; c++)
                Zl[r * 16 + c] = 16.0f * Zl[r * 16 + c] * a_own * bv[c];
        }
    } else if (wid == 1) {
        // H_pre (lanes 0..3) / H_post (lanes 4..7) softmax over 4 streams
        if (lane < 8) {
            const int s = lane & 3;
            const bool pre = lane < 4;
            const float alpha = pre ? alpha_pre_p[0] : alpha_post_p[0];
            const float logit = pre ? H_pre_logits[s] : H_post_logits[s];
            float pv = alpha * scale * extra[pre ? s : 4 + s] + logit;
            float pm = fmaxf(pv, __shfl_xor(pv, 1, 4));
            pm = fmaxf(pm, __shfl_xor(pm, 2, 4));
            float e = __expf(pv - pm);
            float s2 = e + __shfl_xor(e, 1, 4);
            s2 += __shfl_xor(s2, 2, 4);
            float h = e / s2;
            if (pre) hpre[s] = h; else hpost[s] = h;
        }
    }
    __syncthreads();                                   // barrier 3

    // mixed[tc][c] = sum_s S[s][tc] * bus[s*256+c]; add branch*H_post; write out
    float busr[16];
#pragma unroll
    for (int s = 0; s < 16; s++) busr[s] = busf[s * 256 + tid];
#pragma unroll
    for (int tc = 0; tc < 16; tc++) {
        float acc2 = 0.f;
#pragma unroll
        for (int s = 0; s < 16; s++) acc2 += Zl[s * 16 + tc] * busr[s];
        int sout = tc >> 2, d = (tc & 3) * 256 + tid;
        float val = acc2 + bor[tc & 3] * hpost[sout];
        out[((size_t)(b * 4 + sout) * 2048 + l) * 1024 + d] = val;
    }

    // branch_input[d] = sum_s hpre[s] * bus[s*1024+d]
    int d0 = tid * 4;
    float4 bi; bi.x = bi.y = bi.z = bi.w = 0.f;
#pragma unroll
    for (int s = 0; s < 4; s++) {
        float4 v = *(const float4*)&busf[s * 1024 + d0];
        float h = hpre[s];
        bi.x += h * v.x; bi.y += h * v.y; bi.z += h * v.z; bi.w += h * v.w;
    }
    *(float4*)&out[OUT0 + ((size_t)b * 2048 + l) * 1024 + d0] = bi;
}

// ---------------------------------------------------------------------------
extern "C" void kernel_launch(void* const* d_in, const int* in_sizes, int n_in,
                              void* d_out, int out_size, void* d_ws, size_t ws_size,
                              hipStream_t stream) {
    const float* residuals  = (const float*)d_in[0];
    const float* branch_out = (const float*)d_in[1];
    const float* gamma      = (const float*)d_in[2];
    const float* H_res_log  = (const float*)d_in[3];
    const float* phi_res    = (const float*)d_in[4];
    const float* alpha_res  = (const float*)d_in[5];
    const float* H_pre_log  = (const float*)d_in[6];
    const float* phi_pre    = (const float*)d_in[7];
    const float* alpha_pre  = (const float*)d_in[8];
    const float* H_post_log = (const float*)d_in[9];
    const float* phi_post   = (const float*)d_in[10];
    const float* alpha_post = (const float*)d_in[11];

    unsigned short* W = (unsigned short*)d_ws;                       // 288*4096 bf16
    float* raw_part = (float*)((char*)d_ws + (size_t)NPAD * BUSW * 2); // 4*8192*288 f32
    float* out = (float*)d_out;

    hipLaunchKernelGGL(prep_w_kernel, dim3(NPAD * BUSW / 256), dim3(256), 0, stream,
                       gamma, phi_res, phi_pre, phi_post, W);
    hipLaunchKernelGGL(gemm_raw_kernel, dim3(NTOK / BM, KSPLIT), dim3(256), 0, stream,
                       residuals, W, raw_part);
    hipLaunchKernelGGL(fused_tail_kernel, dim3(NTOK), dim3(256), 0, stream,
                       residuals, branch_out, H_res_log, alpha_res,
                       H_pre_log, alpha_pre, H_post_log, alpha_post, raw_part, out);
}

// Round 2
// 383.236 us; speedup vs baseline: 1.1227x; 1.0438x over previous
//
#include <hip/hip_runtime.h>
#include <hip/hip_bf16.h>
#include <math.h>

#define NSTREAM 4
#define DIM     1024
#define BUSW    4096
#define NTOK    8192      // B*L = 4*2048
#define NPAD    288       // 256 (res) + 4 (pre) + 4 (post) + pad to 16*18
#define KSPLIT  4
#define KCH     1024      // BUSW / KSPLIT
#define BM      64
#define BK      32
#define OUT0    ((size_t)16 * 2048 * 1024)   // offset of branch_input in d_out

typedef short bf16x8 __attribute__((ext_vector_type(8)));
typedef float f32x4  __attribute__((ext_vector_type(4)));

__device__ __forceinline__ unsigned short f2bf(float f) {
    union { float f; unsigned int u; } x; x.f = f;
    unsigned int r = x.u + 0x7fffu + ((x.u >> 16) & 1u);
    return (unsigned short)(r >> 16);
}
__device__ __forceinline__ unsigned int pack2(float a, float b) {
    return (unsigned int)f2bf(a) | ((unsigned int)f2bf(b) << 16);
}

// async global->LDS, 16B per lane (wave-uniform LDS base + lane*16 layout)
__device__ __forceinline__ void gload_lds16(const void* g, void* l) {
    __builtin_amdgcn_global_load_lds(
        (const __attribute__((address_space(1))) unsigned int*)g,
        (__attribute__((address_space(3))) unsigned int*)l, 16, 0, 0);
}

// ---------------------------------------------------------------------------
// Kernel 1: pack W''[n][k] = (gamma[k]+1) * [phi_res|phi_pre|phi_post|0][k][n]
// stored N-major, K-fast (bf16) so B-fragments are contiguous 16B reads.
// ---------------------------------------------------------------------------
__global__ void prep_w_kernel(const float* __restrict__ gamma,
                              const float* __restrict__ phi_res,
                              const float* __restrict__ phi_pre,
                              const float* __restrict__ phi_post,
                              unsigned short* __restrict__ W) {
    int idx = blockIdx.x * 256 + threadIdx.x;    // idx = n*4096 + k
    int n = idx >> 12;
    int k = idx & 4095;
    float v = 0.0f;
    if (n < 256)      v = phi_res[k * 256 + n];
    else if (n < 260) v = phi_pre[k * 4 + (n - 256)];
    else if (n < 264) v = phi_post[k * 4 + (n - 260)];
    v *= (gamma[k] + 1.0f);
    W[idx] = f2bf(v);
}

// ---------------------------------------------------------------------------
// Kernel 2: raw_part[kc][token][n] = sum_{k in kc-chunk} bus[token][k]*W''[n][k]
// MFMA 16x16x32 bf16. Block: 256 thr (4 waves), BM=64 tokens x NPAD=288 cols,
// BK=32, split-K over blockIdx.y. Wave w: rows (w>>1)*32, cols (w&1)*144.
// B staged via global_load_lds (async, no VGPR round trip); bfrag loaded
// one-at-a-time to keep VGPR <= 128 for 4 blocks/CU.
// ---------------------------------------------------------------------------
__launch_bounds__(256, 4)
__global__ void gemm_raw_kernel(const float* __restrict__ residuals,
                                const unsigned short* __restrict__ W,
                                float* __restrict__ raw_part) {
    __shared__ __align__(16) unsigned short Alds[BM * BK];      // [row][k], k-fast
    __shared__ __align__(16) unsigned short Blds[NPAD * BK];    // [n][k],   k-fast

    const int tid = threadIdx.x;
    const int wid = tid >> 6, lane = tid & 63;
    const int tb = blockIdx.x, kc = blockIdx.y;
    const int row0 = tb * BM;

    f32x4 acc[2][9];
#pragma unroll
    for (int i = 0; i < 2; i++)
#pragma unroll
        for (int j = 0; j < 9; j++) acc[i][j] = (f32x4){0.f, 0.f, 0.f, 0.f};

    // A staging: thread -> (row = tid/4, 8 consecutive k at (tid%4)*8)
    const int arow = tid >> 2;
    const int akq  = (tid & 3) * 8;
    const int tok  = row0 + arow;
    const int bidx = tok >> 11, lidx = tok & 2047;
    // bus k = kc*1024 + (kt*32 + akq); stream = kc (since chunk < 1024)
    const float* abase = residuals +
        (((size_t)(bidx * 4 + kc) * 2048 + lidx) * 1024 + akq);
    const char* wbytes = (const char*)(W + (size_t)kc * KCH);

    const int fr = lane & 15, hf = lane >> 4;
    const int wr = (wid >> 1) * 32;
    const int wc = (wid & 1) * 144;

    for (int kt = 0; kt < KCH / BK; kt++) {
        // stage B async: 288 rows x 64B = 1152 16B chunks; chunk idx ->
        // LDS byte idx*16 (wave base + lane*16), global rn=idx>>2 ko=(idx&3)*16
#pragma unroll
        for (int i = 0; i < 5; i++) {
            int idx = i * 256 + tid;
            if (idx < (NPAD * BK) / 8) {
                int rn = idx >> 2;
                const void* g = wbytes + (size_t)rn * (BUSW * 2) + kt * (BK * 2)
                                + (idx & 3) * 16;
                gload_lds16(g, (char*)Blds + idx * 16);
            }
        }
        // stage A (fp32 -> bf16, VALU pack)
        const float* ap = abase + kt * BK;
        float4 f0 = *(const float4*)(ap);
        float4 f1 = *(const float4*)(ap + 4);
        uint4 ua;
        ua.x = pack2(f0.x, f0.y); ua.y = pack2(f0.z, f0.w);
        ua.z = pack2(f1.x, f1.y); ua.w = pack2(f1.z, f1.w);
        *(uint4*)&Alds[arow * BK + akq] = ua;
        __syncthreads();

        bf16x8 afrag[2];
#pragma unroll
        for (int mt = 0; mt < 2; mt++)
            afrag[mt] = *(const bf16x8*)&Alds[(wr + mt * 16 + fr) * BK + hf * 8];
#pragma unroll
        for (int nt = 0; nt < 9; nt++) {
            bf16x8 bfrag = *(const bf16x8*)&Blds[(wc + nt * 16 + fr) * BK + hf * 8];
            acc[0][nt] = __builtin_amdgcn_mfma_f32_16x16x32_bf16(
                afrag[0], bfrag, acc[0][nt], 0, 0, 0);
            acc[1][nt] = __builtin_amdgcn_mfma_f32_16x16x32_bf16(
                afrag[1], bfrag, acc[1][nt], 0, 0, 0);
        }
        __syncthreads();
    }

    // epilogue: C/D mapping col=lane&15, row=(lane>>4)*4+reg
#pragma unroll
    for (int mt = 0; mt < 2; mt++)
#pragma unroll
        for (int nt = 0; nt < 9; nt++)
#pragma unroll
            for (int r = 0; r < 4; r++) {
                int token = row0 + wr + mt * 16 + hf * 4 + r;
                int col   = wc + nt * 16 + fr;
                raw_part[((size_t)kc * NTOK + token) * NPAD + col] = acc[mt][nt][r];
            }
}

// ---------------------------------------------------------------------------
// Kernel 3: per-token fused tail. 1 block (256 thr) per token.
// Bus is fully register-resident: thread tid holds busr[j] = bus[j*256+tid]
// (16 coalesced dword loads). sumsq, the 16x16 mix, AND branch_input all
// come from busr (branch_input[q*256+tid] = sum_s hpre[s]*busr[s*4+q]).
// No bus LDS at all; LDS ~1.3KB. Sinkhorn multiplicative-domain on wave 0.
// ---------------------------------------------------------------------------
__global__ void fused_tail_kernel(const float* __restrict__ residuals,
                                  const float* __restrict__ branch_output,
                                  const float* __restrict__ H_res_logits,
                                  const float* __restrict__ alpha_res_p,
                                  const float* __restrict__ H_pre_logits,
                                  const float* __restrict__ alpha_pre_p,
                                  const float* __restrict__ H_post_logits,
                                  const float* __restrict__ alpha_post_p,
                                  const float* __restrict__ raw_part,
                                  float* __restrict__ out) {
    const int t = blockIdx.x;
    const int b = t >> 11, l = t & 2047;
    const int tid = threadIdx.x;
    const int wid = tid >> 6, lane = tid & 63;

    __shared__ float Zl[256];      // K = exp(Z), then overwritten with S
    __shared__ float au[16], bv[16];
    __shared__ float extra[8];
    __shared__ float hpre[4], hpost[4];
    __shared__ float redbuf[4];

    // raw row sums over split-K partials (independent of bus load)
    float rsum = 0.f;
#pragma unroll
    for (int kc = 0; kc < 4; kc++)
        rsum += raw_part[((size_t)kc * NTOK + t) * NPAD + tid];
    float esum = 0.f;
    if (tid < 8) {
#pragma unroll
        for (int kc = 0; kc < 4; kc++)
            esum += raw_part[((size_t)kc * NTOK + t) * NPAD + 256 + tid];
    }

    // bus column-of-16 into registers: busr[j] = bus[j*256 + tid]
    // (stream = j>>2, d = (j&3)*256 + tid) -- each load coalesced.
    const float* rbase = residuals + ((size_t)b * 4 * 2048 + l) * 1024;
    float busr[16];
    float sumsq = 0.f;
#pragma unroll
    for (int j = 0; j < 16; j++) {
        busr[j] = rbase[(size_t)(j >> 2) * 2048 * 1024 + (j & 3) * 256 + tid];
        sumsq += busr[j] * busr[j];
    }
#pragma unroll
    for (int off = 32; off > 0; off >>= 1) sumsq += __shfl_down(sumsq, off, 64);
    if (lane == 0) redbuf[wid] = sumsq;
    __syncthreads();                                   // barrier 1

    const float ss = redbuf[0] + redbuf[1] + redbuf[2] + redbuf[3];
    const float scale = 64.0f / fmaxf(sqrtf(ss), 1e-12f);  // sqrt(4096)/||bus||

    // K = exp(Z); Z = (alpha*scale*raw + logits)/tau. Z in [-161, ~2]: no max
    // subtraction needed; off-diagonal underflow to 0 matches reference ~1e-70.
    const float a_res = alpha_res_p[0];
    Zl[tid] = __expf((a_res * scale * rsum + H_res_logits[tid]) * 20.0f);
    if (tid < 8) extra[tid] = esum;

    // prefetch branch_output while Sinkhorn runs
    const float* bo = branch_output + ((size_t)b * 2048 + l) * 1024;
    float bor[4];
#pragma unroll
    for (int j = 0; j < 4; j++) bor[j] = bo[j * 256 + tid];

    __syncthreads();                                   // barrier 2

    if (wid == 0) {
        // Multiplicative Sinkhorn on lanes 0..15 of wave 0.
        // a[r] = (1/16)/(K b)[r];  b[c] = (1/16)/(K^T a)[c];  10 iterations.
        const float c0 = 1.0f / 16.0f;
        const bool act = lane < 16;
        const int r = lane & 15;
        if (act) bv[r] = 1.0f;
        __builtin_amdgcn_sched_barrier(0);
        float a_own = 0.f;
        for (int it = 0; it < 10; it++) {
            if (act) {
                float s2 = 0.f;
#pragma unroll
                for (int c = 0; c < 16; c++) s2 += Zl[r * 16 + c] * bv[c];
                a_own = c0 / s2;
                au[r] = a_own;
            }
            __builtin_amdgcn_sched_barrier(0);
            if (act) {
                float s2 = 0.f;
#pragma unroll
                for (int rr = 0; rr < 16; rr++) s2 += Zl[rr * 16 + r] * au[rr];
                bv[r] = c0 / s2;
            }
            __builtin_amdgcn_sched_barrier(0);
        }
        // S = 16 * K * a_r * b_c, in place
        if (act) {
#pragma unroll
            for (int c = 0; c < 16; c++)
                Zl[r * 16 + c] = 16.0f * Zl[r * 16 + c] * a_own * bv[c];
        }
    } else if (wid == 1) {
        // H_pre (lanes 0..3) / H_post (lanes 4..7) softmax over 4 streams
        if (lane < 8) {
            const int s = lane & 3;
            const bool pre = lane < 4;
            const float alpha = pre ? alpha_pre_p[0] : alpha_post_p[0];
            const float logit = pre ? H_pre_logits[s] : H_post_logits[s];
            float pv = alpha * scale * extra[pre ? s : 4 + s] + logit;
            float pm = fmaxf(pv, __shfl_xor(pv, 1, 4));
            pm = fmaxf(pm, __shfl_xor(pm, 2, 4));
            float e = __expf(pv - pm);
            float s2 = e + __shfl_xor(e, 1, 4);
            s2 += __shfl_xor(s2, 2, 4);
            float h = e / s2;
            if (pre) hpre[s] = h; else hpost[s] = h;
        }
    }
    __syncthreads();                                   // barrier 3

    // mixed[tc][c] = sum_s S[s][tc] * busr[s]; add branch*H_post; write out
#pragma unroll
    for (int tc = 0; tc < 16; tc++) {
        float acc2 = 0.f;
#pragma unroll
        for (int s = 0; s < 16; s++) acc2 += Zl[s * 16 + tc] * busr[s];
        int sout = tc >> 2, d = (tc & 3) * 256 + tid;
        float val = acc2 + bor[tc & 3] * hpost[sout];
        out[((size_t)(b * 4 + sout) * 2048 + l) * 1024 + d] = val;
    }

    // branch_input[q*256+tid] = sum_s hpre[s] * bus[s*1024 + q*256 + tid]
    //                         = sum_s hpre[s] * busr[s*4 + q]
#pragma unroll
    for (int q = 0; q < 4; q++) {
        float bi = 0.f;
#pragma unroll
        for (int s = 0; s < 4; s++) bi += hpre[s] * busr[s * 4 + q];
        out[OUT0 + ((size_t)b * 2048 + l) * 1024 + q * 256 + tid] = bi;
    }
}

// ---------------------------------------------------------------------------
extern "C" void kernel_launch(void* const* d_in, const int* in_sizes, int n_in,
                              void* d_out, int out_size, void* d_ws, size_t ws_size,
                              hipStream_t stream) {
    const float* residuals  = (const float*)d_in[0];
    const float* branch_out = (const float*)d_in[1];
    const float* gamma      = (const float*)d_in[2];
    const float* H_res_log  = (const float*)d_in[3];
    const float* phi_res    = (const float*)d_in[4];
    const float* alpha_res  = (const float*)d_in[5];
    const float* H_pre_log  = (const float*)d_in[6];
    const float* phi_pre    = (const float*)d_in[7];
    const float* alpha_pre  = (const float*)d_in[8];
    const float* H_post_log = (const float*)d_in[9];
    const float* phi_post   = (const float*)d_in[10];
    const float* alpha_post = (const float*)d_in[11];

    unsigned short* W = (unsigned short*)d_ws;                       // 288*4096 bf16
    float* raw_part = (float*)((char*)d_ws + (size_t)NPAD * BUSW * 2); // 4*8192*288 f32
    float* out = (float*)d_out;

    hipLaunchKernelGGL(prep_w_kernel, dim3(NPAD * BUSW / 256), dim3(256), 0, stream,
                       gamma, phi_res, phi_pre, phi_post, W);
    hipLaunchKernelGGL(gemm_raw_kernel, dim3(NTOK / BM, KSPLIT), dim3(256), 0, stream,
                       residuals, W, raw_part);
    hipLaunchKernelGGL(fused_tail_kernel, dim3(NTOK), dim3(256), 0, stream,
                       residuals, branch_out, H_res_log, alpha_res,
                       H_pre_log, alpha_pre, H_post_log, alpha_post, raw_part, out);
}